// Round 12
// baseline (332.596 us; speedup 1.0000x reference)
//
#include <hip/hip_runtime.h>
#include <hip/hip_fp16.h>

constexpr int HID = 128;
constexpr int DH  = 64;

typedef _Float16 f16x2 __attribute__((ext_vector_type(2)));
typedef _Float16 fh4   __attribute__((ext_vector_type(4)));
typedef _Float16 fh8   __attribute__((ext_vector_type(8)));   // 4 VGPRs, MFMA A/B frag
typedef float    f32x4v __attribute__((ext_vector_type(4)));  // MFMA C/D frag

__device__ __forceinline__ fh8 relu8(fh8 x) {
  fh8 z = {0, 0, 0, 0, 0, 0, 0, 0};
#if __has_builtin(__builtin_elementwise_max)
  return __builtin_elementwise_max(x, z);
#else
  fh8 r;
#pragma unroll
  for (int i = 0; i < 8; i++) r[i] = x[i] > z[i] ? x[i] : z[i];
  return r;
#endif
}

// ---------------- merged: degree count + h->fp16 + W1 fragment table build ----------------
// (round-10 path restored: round-11's per-block scattered w1 LDS build regressed uv)
__global__ void count_h16_frag_kernel(const int* __restrict__ dst, int* __restrict__ counts, int E,
                                      const float* __restrict__ h, _Float16* __restrict__ h16, int total,
                                      const float* __restrict__ w1a, const float* __restrict__ w1b,
                                      _Float16* __restrict__ fragTab) {
  int i = blockIdx.x * 256 + threadIdx.x;
  if (blockIdx.x < 128) {
    int flat = i;
    int rel = flat >> 14;
    int r2 = flat & 16383;
    int g = r2 >> 10, s = (r2 >> 9) & 1, l = (r2 >> 3) & 63, j = r2 & 7;
    int bc = l & 15, bkg = l >> 4;
    int k = s * 32 + bkg * 8 + j;
    int F = rel ? 32 : 64;
    const float* w1 = rel ? w1b : w1a;
    float val = 0.f;
    if (k < F) {
      int jslot = (g & 7) * 16 + bc;
      int krow = (g < 8) ? k : (F + k);
      val = w1[krow * HID + jslot];
    }
    fragTab[flat] = (_Float16)val;
  }
  if (i < E) atomicAdd(&counts[dst[i]], 1);
  int base = i * 8;
  if (base + 7 < total) {
    float4 f0 = *(const float4*)(h + base);
    float4 f1 = *(const float4*)(h + base + 4);
    fh8 t;
    t[0] = (_Float16)f0.x; t[1] = (_Float16)f0.y; t[2] = (_Float16)f0.z; t[3] = (_Float16)f0.w;
    t[4] = (_Float16)f1.x; t[5] = (_Float16)f1.y; t[6] = (_Float16)f1.z; t[7] = (_Float16)f1.w;
    *(fh8*)(h16 + base) = t;
  }
}

// ---------------- uv precompute via MFMA, transposed (round-10 version, fragTab LDS copy) ---
__launch_bounds__(256)
__global__ void uv_mfma_kernel(const float* __restrict__ pca, const float* __restrict__ pimg,
                               const float* __restrict__ b1a, const float* __restrict__ b1b,
                               const _Float16* __restrict__ fragTab,
                               _Float16* __restrict__ u_cat, _Float16* __restrict__ v_cat, int N) {
  __shared__ _Float16 sB[16384];   // [g(16)][s(2)][l(64)][j(8)]
  int rel = blockIdx.y;
  const float* feat = rel ? pimg : pca;
  const float* b1   = rel ? b1b : b1a;
  int F  = rel ? 32 : 64;
  int KS = rel ? 1 : 2;
  int tid = threadIdx.x;
  {
    const fh8* srcp = (const fh8*)(fragTab + rel * 16384);
    fh8* dstp = (fh8*)sB;
    for (int i = tid; i < 2048; i += 256) dstp[i] = srcp[i];
  }
  __syncthreads();
  int lane = tid & 63, w = tid >> 6;
  int c = lane & 15, kg = lane >> 4;
  int node = blockIdx.x * 64 + w * 16 + c;          // B-fragment: col = node
  int nclamp = node < N ? node : N - 1;
  fh8 bfeat[2];
#pragma unroll
  for (int s = 0; s < 2; s++) {
    if (s < KS) {
      const float* fp = feat + (size_t)nclamp * F + s * 32 + kg * 8;
      float4 f0 = *(const float4*)fp;
      float4 f1 = *(const float4*)(fp + 4);
      fh8 t;
      t[0] = (_Float16)f0.x; t[1] = (_Float16)f0.y; t[2] = (_Float16)f0.z; t[3] = (_Float16)f0.w;
      t[4] = (_Float16)f1.x; t[5] = (_Float16)f1.y; t[6] = (_Float16)f1.z; t[7] = (_Float16)f1.w;
      bfeat[s] = t;
    }
  }
  float4 b1q[8];
#pragma unroll
  for (int g = 0; g < 8; g++) b1q[g] = *(const float4*)(b1 + g * 16 + kg * 4);

  bool wr = node < N;
#pragma unroll
  for (int g = 0; g < 16; g++) {
    f32x4v acc = {0.f, 0.f, 0.f, 0.f};
    acc = __builtin_amdgcn_mfma_f32_16x16x32_f16(((const fh8*)sB)[(g * 2 + 0) * 64 + lane], bfeat[0], acc, 0, 0, 0);
    if (KS == 2)
      acc = __builtin_amdgcn_mfma_f32_16x16x32_f16(((const fh8*)sB)[(g * 2 + 1) * 64 + lane], bfeat[1], acc, 0, 0, 0);
    bool isv = g >= 8;
    int jbase = (g & 7) * 16 + kg * 4;
    float4 bias = isv ? b1q[g & 7] : make_float4(0.f, 0.f, 0.f, 0.f);
    fh4 pk;
    pk[0] = (_Float16)(acc[0] + bias.x);
    pk[1] = (_Float16)(acc[1] + bias.y);
    pk[2] = (_Float16)(acc[2] + bias.z);
    pk[3] = (_Float16)(acc[3] + bias.w);
    _Float16* outp = isv ? v_cat : u_cat;
    if (wr) *(fh4*)(outp + (size_t)node * 256 + rel * 128 + jbase) = pk;
  }
}

// ---------------- CSR scans ----------------
__launch_bounds__(256)
__global__ void scan1_kernel(const int* __restrict__ counts, int* __restrict__ bsums, int N) {
  int b = blockIdx.x, tid = threadIdx.x;
  int base = b * 1024 + tid * 4;
  int s = 0;
  if (base + 3 < N) {
    int4 v = *(const int4*)(counts + base);
    s = v.x + v.y + v.z + v.w;
  } else {
    for (int q = 0; q < 4; q++) { int idx = base + q; if (idx < N) s += counts[idx]; }
  }
#pragma unroll
  for (int o = 32; o >= 1; o >>= 1) s += __shfl_xor(s, o);
  __shared__ int ws[4];
  if ((tid & 63) == 0) ws[tid >> 6] = s;
  __syncthreads();
  if (tid == 0) bsums[b] = ws[0] + ws[1] + ws[2] + ws[3];
}

__launch_bounds__(256)
__global__ void scan23_kernel(const int* __restrict__ counts, const int* __restrict__ bsums,
                              int* __restrict__ offsets, int* __restrict__ cursor,
                              int NB, int N, int E) {
  int b = blockIdx.x, tid = threadIdx.x, lane = tid & 63, w = tid >> 6;
  __shared__ int s_bpre;
  if (tid < 64) {
    int v = (lane < NB) ? bsums[lane] : 0;
    int incl = v;
#pragma unroll
    for (int o = 1; o < 64; o <<= 1) { int t = __shfl_up(incl, o); if (lane >= o) incl += t; }
    int excl = incl - v;
    int t = __shfl(excl, b);
    if (lane == 0) s_bpre = t;
  }
  __syncthreads();
  int base = b * 1024 + tid * 4;
  int c[4] = {0, 0, 0, 0};
  if (base + 3 < N) {
    int4 v = *(const int4*)(counts + base);
    c[0] = v.x; c[1] = v.y; c[2] = v.z; c[3] = v.w;
  } else {
    for (int q = 0; q < 4; q++) { int idx = base + q; if (idx < N) c[q] = counts[idx]; }
  }
  int s = c[0] + c[1] + c[2] + c[3];
  int incl = s;
#pragma unroll
  for (int o = 1; o < 64; o <<= 1) { int t = __shfl_up(incl, o); if (lane >= o) incl += t; }
  int excl = incl - s;
  __shared__ int ws[4];
  if (lane == 63) ws[w] = incl;
  __syncthreads();
  int wpre = 0;
  for (int q = 0; q < w; q++) wpre += ws[q];
  int off = s_bpre + wpre + excl;
  for (int q = 0; q < 4; q++) {
    int idx = base + q;
    if (idx < N) { offsets[idx] = off; cursor[idx] = off; }
    off += c[q];
  }
  if (b == 0 && tid == 0) offsets[N] = E;
}

__global__ void fill_kernel(const int* __restrict__ src, const int* __restrict__ dst,
                            int* __restrict__ cursor, int2* __restrict__ edges, int E) {
  int e = blockIdx.x * 256 + threadIdx.x;
  if (e < E) {
    int d = dst[e];
    int pos = atomicAdd(&cursor[d], 1);
    edges[pos] = make_int2(src[e], d);
  }
}

// ---------------- FUSED score + softmax + aggregate ----------------
// Wave w owns nodes {n : offsets[n]>>6 == w} (two binary searches). A node's edges are
// never split across waves (span < 64+maxdeg, chunked by 64). Per chunk: MFMA-score 64
// edges -> ek into per-wave LDS (fp16) + src staging, then inline segmented aggregation
// with normalize-on-node-boundary. Kills ek global round-trip (25.6MB) + the agg dispatch;
// agg's VALU/h-gather hides in score's memory-stall shadow (score was VALUBusy 16%).
__launch_bounds__(256, 6)
__global__ void fused_kernel(const _Float16* __restrict__ u_cat, const _Float16* __restrict__ v_cat,
                             const int2* __restrict__ edges, const int* __restrict__ offsets,
                             const _Float16* __restrict__ h16,
                             const float* __restrict__ w2a, const float* __restrict__ w2b,
                             const float* __restrict__ b2a, const float* __restrict__ b2b,
                             float* __restrict__ out, int N, int NW) {
  __shared__ _Float16 sB[4096];                       // w2 B-fragments (block-diag), 8KB
  __shared__ __align__(16) _Float16 s_ek[4][64][8];   // per-wave ek staging, 4KB
  __shared__ int s_src[4][64];                        // per-wave src staging, 1KB
  int tid = threadIdx.x, lane = tid & 63, wv = tid >> 6;
  int col = lane & 15, kg = lane >> 4;
  for (int idx = tid; idx < 4096; idx += 256) {
    int t = idx >> 9, l = (idx >> 3) & 63, j = idx & 7;
    int bc = l & 15;
    int k = t * 32 + ((l >> 4) << 3) + j;
    float val = 0.f;
    if (bc < 4) { if (k < 128) val = w2a[k * 4 + bc]; }
    else if (bc < 8) { if (k >= 128) val = w2b[(k - 128) * 4 + (bc - 4)]; }
    sB[idx] = (_Float16)val;
  }
  __syncthreads();

  int w = blockIdx.x * 4 + wv;
  if (w >= NW) return;
  int t0 = w * 64, t1 = t0 + 64;
  // lower_bound over offsets[0..N) for t0 and t1 (wave-uniform)
  int lo = 0, hi = N;
  while (lo < hi) { int mid = (lo + hi) >> 1; if (offsets[mid] < t0) lo = mid + 1; else hi = mid; }
  int nlo = lo;
  hi = N;
  while (lo < hi) { int mid = (lo + hi) >> 1; if (offsets[mid] < t1) lo = mid + 1; else hi = mid; }
  int nhi = lo;
  if (nlo >= nhi) return;                 // owns no nodes
  int e_begin = offsets[nlo], e_end = offsets[nhi];

  float b2v = (col < 4) ? b2a[col] : ((col < 8) ? b2b[col - 4] : 0.f);

  int cur = nlo;
  int node_start = e_begin;
  int boundary = offsets[cur + 1];        // cur <= nhi-1 always when read
  float accO[8] = {0, 0, 0, 0, 0, 0, 0, 0};
  float ssum[8] = {0, 0, 0, 0, 0, 0, 0, 0};

  for (int cb = e_begin; cb < e_end; cb += 64) {
    __builtin_amdgcn_wave_barrier();      // keep prev chunk's LDS reads before new writes
    // ---- score 64 edges [cb, cb+64) via MFMA ----
    const _Float16* up[4];
    const _Float16* vp[4];
    int srcs[4];
#pragma unroll
    for (int m = 0; m < 4; m++) {
      int em = cb + m * 16 + col;
      int ec = em < e_end ? em : e_end - 1;   // clamp; masked slots never consumed
      int2 sd = edges[ec];
      srcs[m] = sd.x;
      up[m] = u_cat + (size_t)sd.x * 256 + kg * 8;
      vp[m] = v_cat + (size_t)sd.y * 256 + kg * 8;
    }
    f32x4v acc[4];
#pragma unroll
    for (int m = 0; m < 4; m++) acc[m] = (f32x4v){0.f, 0.f, 0.f, 0.f};
#pragma unroll
    for (int t = 0; t < 8; t++) {
      fh8 bf = *(const fh8*)(sB + ((t * 64 + lane) << 3));
#pragma unroll
      for (int m = 0; m < 4; m++) {
        fh8 uu = *(const fh8*)(up[m] + t * 32);
        fh8 vv = *(const fh8*)(vp[m] + t * 32);
        acc[m] = __builtin_amdgcn_mfma_f32_16x16x32_f16(relu8(uu + vv), bf, acc[m], 0, 0, 0);
      }
    }
    if (kg == 0) {
#pragma unroll
      for (int m = 0; m < 4; m++) s_src[wv][m * 16 + col] = srcs[m];
    }
    if (col < 8) {
#pragma unroll
      for (int m = 0; m < 4; m++) {
#pragma unroll
        for (int q = 0; q < 4; q++) {
          float x = acc[m][q] + b2v;
          x = x > 0.f ? x : 0.01f * x;
          s_ek[wv][m * 16 + kg * 4 + q][col] = (_Float16)__expf(x);
        }
      }
    }
    __builtin_amdgcn_wave_barrier();
    asm volatile("s_waitcnt lgkmcnt(0)" ::: "memory");   // LDS writes visible to this wave
    // ---- aggregate this chunk's edges with node-boundary handling ----
    int cnt = min(64, e_end - cb);
    for (int jj = 0; jj < cnt; jj++) {
      int e = cb + jj;
      while (e == boundary) {             // finalize node cur (wave-uniform)
        int deg = boundary - node_start;
        float* op = out + (size_t)cur * 512;
        if (deg == 0) {
#pragma unroll
          for (int k = 0; k < 4; k++) { op[k * 128 + lane] = 0.f; op[k * 128 + 64 + lane] = 0.f; }
        } else {
#pragma unroll
          for (int k = 0; k < 8; k++) {
            float rsv = 1.f / ssum[k];
            int colo = k < 4 ? k * 128 + lane : (k - 4) * 128 + 64 + lane;
            op[colo] = accO[k] * rsv;
          }
        }
#pragma unroll
        for (int k = 0; k < 8; k++) { accO[k] = 0.f; ssum[k] = 0.f; }
        node_start = boundary; cur++;
        boundary = offsets[cur + 1];      // never past nhi-1 inside loop (e < e_end)
      }
      fh8 ea = *(const fh8*)(&s_ek[wv][jj][0]);   // ds_read_b128 broadcast
      int sa = s_src[wv][jj];
      float hv = (float)h16[(size_t)sa * DH + lane];
#pragma unroll
      for (int k = 0; k < 8; k++) {
        float ev = (float)ea[k];
        accO[k] = fmaf(ev, hv, accO[k]);
        ssum[k] += ev;
      }
    }
  }
  // finalize remaining nodes [cur, nhi)  (last in-progress node + trailing empties)
  while (cur < nhi) {
    int bnd = offsets[cur + 1];
    int deg = bnd - node_start;
    float* op = out + (size_t)cur * 512;
    if (deg == 0) {
#pragma unroll
      for (int k = 0; k < 4; k++) { op[k * 128 + lane] = 0.f; op[k * 128 + 64 + lane] = 0.f; }
    } else {
#pragma unroll
      for (int k = 0; k < 8; k++) {
        float rsv = 1.f / ssum[k];
        int colo = k < 4 ? k * 128 + lane : (k - 4) * 128 + 64 + lane;
        op[colo] = accO[k] * rsv;
      }
    }
#pragma unroll
    for (int k = 0; k < 8; k++) { accO[k] = 0.f; ssum[k] = 0.f; }
    node_start = bnd; cur++;
  }
}

extern "C" void kernel_launch(void* const* d_in, const int* in_sizes, int n_in,
                              void* d_out, int out_size, void* d_ws, size_t ws_size,
                              hipStream_t stream) {
  const float* h      = (const float*)d_in[0];
  const float* pca    = (const float*)d_in[1];
  const float* pimg   = (const float*)d_in[2];
  const float* pca_w1 = (const float*)d_in[3];
  const float* pca_b1 = (const float*)d_in[4];
  const float* pca_w2 = (const float*)d_in[5];
  const float* pca_b2 = (const float*)d_in[6];
  const float* pi_w1  = (const float*)d_in[7];
  const float* pi_b1  = (const float*)d_in[8];
  const float* pi_w2  = (const float*)d_in[9];
  const float* pi_b2  = (const float*)d_in[10];
  const int*   src    = (const int*)d_in[11];
  const int*   dst    = (const int*)d_in[12];
  int N = in_sizes[0] / 64;
  int E = in_sizes[11];
  float* out = (float*)d_out;

  char* ws = (char*)d_ws;
  size_t o = 0;
  auto alloc = [&](size_t bytes) { void* p = ws + o; o += (bytes + 255) & ~(size_t)255; return p; };
  _Float16* u_cat  = (_Float16*)alloc((size_t)N * 256 * 2);
  _Float16* v_cat  = (_Float16*)alloc((size_t)N * 256 * 2);
  _Float16* h16    = (_Float16*)alloc((size_t)N * 64 * 2);
  _Float16* fragTab = (_Float16*)alloc(32768 * 2);
  int* counts  = (int*)alloc((size_t)N * 4);
  int* cursor  = (int*)alloc((size_t)N * 4);
  int* offsets = (int*)alloc((size_t)(N + 1) * 4);
  int* bsums   = (int*)alloc(1024 * 4);
  int2* edges  = (int2*)alloc((size_t)E * 8);

  hipMemsetAsync(counts, 0, (size_t)N * 4, stream);

  count_h16_frag_kernel<<<(E + 255) / 256, 256, 0, stream>>>(dst, counts, E, h, h16, N * 64,
                                                             pca_w1, pi_w1, fragTab);
  dim3 uvgrid((N + 63) / 64, 2);
  uv_mfma_kernel<<<uvgrid, 256, 0, stream>>>(pca, pimg, pca_b1, pi_b1, fragTab, u_cat, v_cat, N);
  int NB = (N + 1023) / 1024;
  scan1_kernel<<<NB, 256, 0, stream>>>(counts, bsums, N);
  scan23_kernel<<<NB, 256, 0, stream>>>(counts, bsums, offsets, cursor, NB, N, E);
  fill_kernel<<<(E + 255) / 256, 256, 0, stream>>>(src, dst, cursor, edges, E);
  int NW = (E + 63) / 64;
  fused_kernel<<<(NW + 3) / 4, 256, 0, stream>>>(u_cat, v_cat, edges, offsets, h16,
                                                 pca_w2, pi_w2, pca_b2, pi_b2, out, N, NW);
}

// Round 13
// 286.310 us; speedup vs baseline: 1.1617x; 1.1617x over previous
//
#include <hip/hip_runtime.h>
#include <hip/hip_fp16.h>

constexpr int HID = 128;
constexpr int DH  = 64;

typedef _Float16 f16x2 __attribute__((ext_vector_type(2)));
typedef _Float16 fh4   __attribute__((ext_vector_type(4)));
typedef _Float16 fh8   __attribute__((ext_vector_type(8)));   // 4 VGPRs, MFMA A/B frag
typedef float    f32x4v __attribute__((ext_vector_type(4)));  // MFMA C/D frag

__device__ __forceinline__ fh8 relu8(fh8 x) {
  fh8 z = {0, 0, 0, 0, 0, 0, 0, 0};
#if __has_builtin(__builtin_elementwise_max)
  return __builtin_elementwise_max(x, z);
#else
  fh8 r;
#pragma unroll
  for (int i = 0; i < 8; i++) r[i] = x[i] > z[i] ? x[i] : z[i];
  return r;
#endif
}

// ---------------- merged: degree count + h->fp16 + W1 fragment table build (round 10) ------
__global__ void count_h16_frag_kernel(const int* __restrict__ dst, int* __restrict__ counts, int E,
                                      const float* __restrict__ h, _Float16* __restrict__ h16, int total,
                                      const float* __restrict__ w1a, const float* __restrict__ w1b,
                                      _Float16* __restrict__ fragTab) {
  int i = blockIdx.x * 256 + threadIdx.x;
  if (blockIdx.x < 128) {
    int flat = i;
    int rel = flat >> 14;
    int r2 = flat & 16383;
    int g = r2 >> 10, s = (r2 >> 9) & 1, l = (r2 >> 3) & 63, j = r2 & 7;
    int bc = l & 15, bkg = l >> 4;
    int k = s * 32 + bkg * 8 + j;
    int F = rel ? 32 : 64;
    const float* w1 = rel ? w1b : w1a;
    float val = 0.f;
    if (k < F) {
      int jslot = (g & 7) * 16 + bc;
      int krow = (g < 8) ? k : (F + k);
      val = w1[krow * HID + jslot];
    }
    fragTab[flat] = (_Float16)val;
  }
  if (i < E) atomicAdd(&counts[dst[i]], 1);
  int base = i * 8;
  if (base + 7 < total) {
    float4 f0 = *(const float4*)(h + base);
    float4 f1 = *(const float4*)(h + base + 4);
    fh8 t;
    t[0] = (_Float16)f0.x; t[1] = (_Float16)f0.y; t[2] = (_Float16)f0.z; t[3] = (_Float16)f0.w;
    t[4] = (_Float16)f1.x; t[5] = (_Float16)f1.y; t[6] = (_Float16)f1.z; t[7] = (_Float16)f1.w;
    *(fh8*)(h16 + base) = t;
  }
}

// ---------------- uv precompute via MFMA, transposed, fragTab LDS copy (round 10) -----------
__launch_bounds__(256)
__global__ void uv_mfma_kernel(const float* __restrict__ pca, const float* __restrict__ pimg,
                               const float* __restrict__ b1a, const float* __restrict__ b1b,
                               const _Float16* __restrict__ fragTab,
                               _Float16* __restrict__ u_cat, _Float16* __restrict__ v_cat, int N) {
  __shared__ _Float16 sB[16384];   // [g(16)][s(2)][l(64)][j(8)]
  int rel = blockIdx.y;
  const float* feat = rel ? pimg : pca;
  const float* b1   = rel ? b1b : b1a;
  int F  = rel ? 32 : 64;
  int KS = rel ? 1 : 2;
  int tid = threadIdx.x;
  {
    const fh8* srcp = (const fh8*)(fragTab + rel * 16384);
    fh8* dstp = (fh8*)sB;
    for (int i = tid; i < 2048; i += 256) dstp[i] = srcp[i];
  }
  __syncthreads();
  int lane = tid & 63, w = tid >> 6;
  int c = lane & 15, kg = lane >> 4;
  int node = blockIdx.x * 64 + w * 16 + c;          // B-fragment: col = node
  int nclamp = node < N ? node : N - 1;
  fh8 bfeat[2];
#pragma unroll
  for (int s = 0; s < 2; s++) {
    if (s < KS) {
      const float* fp = feat + (size_t)nclamp * F + s * 32 + kg * 8;
      float4 f0 = *(const float4*)fp;
      float4 f1 = *(const float4*)(fp + 4);
      fh8 t;
      t[0] = (_Float16)f0.x; t[1] = (_Float16)f0.y; t[2] = (_Float16)f0.z; t[3] = (_Float16)f0.w;
      t[4] = (_Float16)f1.x; t[5] = (_Float16)f1.y; t[6] = (_Float16)f1.z; t[7] = (_Float16)f1.w;
      bfeat[s] = t;
    }
  }
  float4 b1q[8];
#pragma unroll
  for (int g = 0; g < 8; g++) b1q[g] = *(const float4*)(b1 + g * 16 + kg * 4);

  bool wr = node < N;
#pragma unroll
  for (int g = 0; g < 16; g++) {
    f32x4v acc = {0.f, 0.f, 0.f, 0.f};
    acc = __builtin_amdgcn_mfma_f32_16x16x32_f16(((const fh8*)sB)[(g * 2 + 0) * 64 + lane], bfeat[0], acc, 0, 0, 0);
    if (KS == 2)
      acc = __builtin_amdgcn_mfma_f32_16x16x32_f16(((const fh8*)sB)[(g * 2 + 1) * 64 + lane], bfeat[1], acc, 0, 0, 0);
    bool isv = g >= 8;
    int jbase = (g & 7) * 16 + kg * 4;
    float4 bias = isv ? b1q[g & 7] : make_float4(0.f, 0.f, 0.f, 0.f);
    fh4 pk;
    pk[0] = (_Float16)(acc[0] + bias.x);
    pk[1] = (_Float16)(acc[1] + bias.y);
    pk[2] = (_Float16)(acc[2] + bias.z);
    pk[3] = (_Float16)(acc[3] + bias.w);
    _Float16* outp = isv ? v_cat : u_cat;
    if (wr) *(fh4*)(outp + (size_t)node * 256 + rel * 128 + jbase) = pk;
  }
}

// ---------------- CSR scans ----------------
__launch_bounds__(256)
__global__ void scan1_kernel(const int* __restrict__ counts, int* __restrict__ bsums, int N) {
  int b = blockIdx.x, tid = threadIdx.x;
  int base = b * 1024 + tid * 4;
  int s = 0;
  if (base + 3 < N) {
    int4 v = *(const int4*)(counts + base);
    s = v.x + v.y + v.z + v.w;
  } else {
    for (int q = 0; q < 4; q++) { int idx = base + q; if (idx < N) s += counts[idx]; }
  }
#pragma unroll
  for (int o = 32; o >= 1; o >>= 1) s += __shfl_xor(s, o);
  __shared__ int ws[4];
  if ((tid & 63) == 0) ws[tid >> 6] = s;
  __syncthreads();
  if (tid == 0) bsums[b] = ws[0] + ws[1] + ws[2] + ws[3];
}

// merged scan2+scan3 (round 11): writes offsets AND cursor, drops 1-block scan + d2d memcpy
__launch_bounds__(256)
__global__ void scan23_kernel(const int* __restrict__ counts, const int* __restrict__ bsums,
                              int* __restrict__ offsets, int* __restrict__ cursor,
                              int NB, int N, int E) {
  int b = blockIdx.x, tid = threadIdx.x, lane = tid & 63, w = tid >> 6;
  __shared__ int s_bpre;
  if (tid < 64) {
    int v = (lane < NB) ? bsums[lane] : 0;
    int incl = v;
#pragma unroll
    for (int o = 1; o < 64; o <<= 1) { int t = __shfl_up(incl, o); if (lane >= o) incl += t; }
    int excl = incl - v;
    int t = __shfl(excl, b);
    if (lane == 0) s_bpre = t;
  }
  __syncthreads();
  int base = b * 1024 + tid * 4;
  int c[4] = {0, 0, 0, 0};
  if (base + 3 < N) {
    int4 v = *(const int4*)(counts + base);
    c[0] = v.x; c[1] = v.y; c[2] = v.z; c[3] = v.w;
  } else {
    for (int q = 0; q < 4; q++) { int idx = base + q; if (idx < N) c[q] = counts[idx]; }
  }
  int s = c[0] + c[1] + c[2] + c[3];
  int incl = s;
#pragma unroll
  for (int o = 1; o < 64; o <<= 1) { int t = __shfl_up(incl, o); if (lane >= o) incl += t; }
  int excl = incl - s;
  __shared__ int ws[4];
  if (lane == 63) ws[w] = incl;
  __syncthreads();
  int wpre = 0;
  for (int q = 0; q < w; q++) wpre += ws[q];
  int off = s_bpre + wpre + excl;
  for (int q = 0; q < 4; q++) {
    int idx = base + q;
    if (idx < N) { offsets[idx] = off; cursor[idx] = off; }
    off += c[q];
  }
  if (b == 0 && tid == 0) offsets[N] = E;
}

__global__ void fill_kernel(const int* __restrict__ src, const int* __restrict__ dst,
                            int* __restrict__ cursor, int2* __restrict__ edges, int E) {
  int e = blockIdx.x * 256 + threadIdx.x;
  if (e < E) {
    int d = dst[e];
    int pos = atomicAdd(&cursor[d], 1);
    edges[pos] = make_int2(src[e], d);
  }
}

// ---------------- MFMA per-edge scores -> ek = exp(leaky_relu(mlp)), fp16 (frozen) ---------
// 4 rounds stable at 87us / 205MB L2-miss @ ~2.5 TB/s = random-gather fabric wall.
__launch_bounds__(256, 8)
__global__ void score_kernel(const _Float16* __restrict__ u_cat, const _Float16* __restrict__ v_cat,
                             const int2* __restrict__ edges,
                             const float* __restrict__ w2a, const float* __restrict__ w2b,
                             const float* __restrict__ b2a, const float* __restrict__ b2b,
                             _Float16* __restrict__ ek, int E) {
  __shared__ _Float16 sB[8 * 64 * 8];   // [t][lane][j] B-fragments of W2cat (block-diag)
  int tid = threadIdx.x, lane = tid & 63, w = tid >> 6;
  int col = lane & 15, kg = lane >> 4;
  for (int idx = tid; idx < 4096; idx += 256) {
    int t = idx >> 9, l = (idx >> 3) & 63, j = idx & 7;
    int bc = l & 15;
    int k = t * 32 + ((l >> 4) << 3) + j;
    float val = 0.f;
    if (bc < 4) { if (k < 128) val = w2a[k * 4 + bc]; }
    else if (bc < 8) { if (k >= 128) val = w2b[(k - 128) * 4 + (bc - 4)]; }
    sB[idx] = (_Float16)val;
  }
  __syncthreads();

  int ebase = blockIdx.x * 256 + w * 64;
  const _Float16* up[4];
  const _Float16* vp[4];
#pragma unroll
  for (int m = 0; m < 4; m++) {
    int em = ebase + m * 16 + col;
    int ec = em < E ? em : 0;          // clamp; epilogue guards stores
    int2 sd = edges[ec];
    up[m] = u_cat + (size_t)sd.x * 256 + kg * 8;
    vp[m] = v_cat + (size_t)sd.y * 256 + kg * 8;
  }

  f32x4v acc[4];
#pragma unroll
  for (int m = 0; m < 4; m++) acc[m] = (f32x4v){0.f, 0.f, 0.f, 0.f};

#pragma unroll
  for (int t = 0; t < 8; t++) {
    fh8 bf = *(const fh8*)(sB + ((t * 64 + lane) << 3));
#pragma unroll
    for (int m = 0; m < 4; m++) {
      fh8 uu = *(const fh8*)(up[m] + t * 32);
      fh8 vv = *(const fh8*)(vp[m] + t * 32);
      acc[m] = __builtin_amdgcn_mfma_f32_16x16x32_f16(relu8(uu + vv), bf, acc[m], 0, 0, 0);
    }
  }

  if (col < 8) {
    float b2v = (col < 4) ? b2a[col] : b2b[col - 4];
#pragma unroll
    for (int m = 0; m < 4; m++) {
#pragma unroll
      for (int q = 0; q < 4; q++) {
        int er = ebase + m * 16 + kg * 4 + q;
        if (er < E) {
          float x = acc[m][q] + b2v;
          x = x > 0.f ? x : 0.01f * x;
          ek[(size_t)er * 8 + col] = (_Float16)__expf(x);
        }
      }
    }
  }
}

// ---------------- softmax-normalize + aggregate (EXACT round-9 structure) -------------------
// Round-9 config totaled 290 with this kernel under 87us; round-10 lane-half split (101us,
// 2.3e7 LDS conflicts) and round-12 fusion (220us) both regressed. Full-wave rows, 4-edge
// unroll, zero shuffles, one pass.
__launch_bounds__(256, 8)
__global__ void agg_kernel(const _Float16* __restrict__ ek, const int2* __restrict__ edges,
                           const int* __restrict__ offsets, const _Float16* __restrict__ h16,
                           float* __restrict__ out, int N) {
  int wid = blockIdx.x * 4 + (threadIdx.x >> 6);
  int lane = threadIdx.x & 63;
  if (wid >= N) return;
  int off0 = offsets[wid], off1 = offsets[wid + 1];
  int deg = off1 - off0;
  float* op = out + (size_t)wid * 512;
  if (deg == 0) {
#pragma unroll
    for (int k = 0; k < 4; k++) { op[k * 128 + lane] = 0.f; op[k * 128 + 64 + lane] = 0.f; }
    return;
  }
  float accO[8] = {0, 0, 0, 0, 0, 0, 0, 0};
  float ssum[8] = {0, 0, 0, 0, 0, 0, 0, 0};
  int last = off1 - 1;
  for (int jj = 0; jj < deg; jj += 4) {
    int i0 = off0 + jj;
    int i1 = min(i0 + 1, last), i2 = min(i0 + 2, last), i3 = min(i0 + 3, last);
    bool m1 = jj + 1 < deg, m2 = jj + 2 < deg, m3 = jj + 3 < deg;
    int s0 = edges[i0].x, s1 = edges[i1].x, s2 = edges[i2].x, s3 = edges[i3].x;
    fh8 e0 = *(const fh8*)(ek + (size_t)i0 * 8);
    fh8 e1 = *(const fh8*)(ek + (size_t)i1 * 8);
    fh8 e2 = *(const fh8*)(ek + (size_t)i2 * 8);
    fh8 e3 = *(const fh8*)(ek + (size_t)i3 * 8);
    float hv0 = (float)h16[(size_t)s0 * DH + lane];
    float hv1 = (float)h16[(size_t)s1 * DH + lane];
    float hv2 = (float)h16[(size_t)s2 * DH + lane];
    float hv3 = (float)h16[(size_t)s3 * DH + lane];
#pragma unroll
    for (int k = 0; k < 8; k++) {
      float e0v = (float)e0[k];
      float e1v = m1 ? (float)e1[k] : 0.f;
      float e2v = m2 ? (float)e2[k] : 0.f;
      float e3v = m3 ? (float)e3[k] : 0.f;
      accO[k] = fmaf(e0v, hv0, accO[k]);
      accO[k] = fmaf(e1v, hv1, accO[k]);
      accO[k] = fmaf(e2v, hv2, accO[k]);
      accO[k] = fmaf(e3v, hv3, accO[k]);
      ssum[k] += (e0v + e1v) + (e2v + e3v);
    }
  }
#pragma unroll
  for (int k = 0; k < 8; k++) {
    float rsv = 1.f / ssum[k];
    int colo = k < 4 ? k * 128 + lane : (k - 4) * 128 + 64 + lane;
    op[colo] = accO[k] * rsv;
  }
}

extern "C" void kernel_launch(void* const* d_in, const int* in_sizes, int n_in,
                              void* d_out, int out_size, void* d_ws, size_t ws_size,
                              hipStream_t stream) {
  const float* h      = (const float*)d_in[0];
  const float* pca    = (const float*)d_in[1];
  const float* pimg   = (const float*)d_in[2];
  const float* pca_w1 = (const float*)d_in[3];
  const float* pca_b1 = (const float*)d_in[4];
  const float* pca_w2 = (const float*)d_in[5];
  const float* pca_b2 = (const float*)d_in[6];
  const float* pi_w1  = (const float*)d_in[7];
  const float* pi_b1  = (const float*)d_in[8];
  const float* pi_w2  = (const float*)d_in[9];
  const float* pi_b2  = (const float*)d_in[10];
  const int*   src    = (const int*)d_in[11];
  const int*   dst    = (const int*)d_in[12];
  int N = in_sizes[0] / 64;
  int E = in_sizes[11];
  float* out = (float*)d_out;

  char* ws = (char*)d_ws;
  size_t o = 0;
  auto alloc = [&](size_t bytes) { void* p = ws + o; o += (bytes + 255) & ~(size_t)255; return p; };
  _Float16* u_cat  = (_Float16*)alloc((size_t)N * 256 * 2);
  _Float16* v_cat  = (_Float16*)alloc((size_t)N * 256 * 2);
  _Float16* h16    = (_Float16*)alloc((size_t)N * 64 * 2);
  _Float16* fragTab = (_Float16*)alloc(32768 * 2);
  int* counts  = (int*)alloc((size_t)N * 4);
  int* cursor  = (int*)alloc((size_t)N * 4);
  int* offsets = (int*)alloc((size_t)(N + 1) * 4);
  int* bsums   = (int*)alloc(1024 * 4);
  int2* edges  = (int2*)alloc((size_t)E * 8);
  _Float16* ekb = (_Float16*)alloc((size_t)E * 8 * 2);

  hipMemsetAsync(counts, 0, (size_t)N * 4, stream);

  count_h16_frag_kernel<<<(E + 255) / 256, 256, 0, stream>>>(dst, counts, E, h, h16, N * 64,
                                                             pca_w1, pi_w1, fragTab);
  dim3 uvgrid((N + 63) / 64, 2);
  uv_mfma_kernel<<<uvgrid, 256, 0, stream>>>(pca, pimg, pca_b1, pi_b1, fragTab, u_cat, v_cat, N);
  int NB = (N + 1023) / 1024;
  scan1_kernel<<<NB, 256, 0, stream>>>(counts, bsums, N);
  scan23_kernel<<<NB, 256, 0, stream>>>(counts, bsums, offsets, cursor, NB, N, E);
  fill_kernel<<<(E + 255) / 256, 256, 0, stream>>>(src, dst, cursor, edges, E);
  score_kernel<<<(E + 255) / 256, 256, 0, stream>>>(u_cat, v_cat, edges,
                                                    pca_w2, pi_w2, pca_b2, pi_b2, ekb, E);
  agg_kernel<<<(N + 3) / 4, 256, 0, stream>>>(ekb, edges, offsets, h16, out, N);
}